// Round 8
// baseline (147.102 us; speedup 1.0000x reference)
//
#include <hip/hip_runtime.h>

#define EPS 1e-8f

// Shapes fixed per reference: x [B=8, N=8192, D=512] fp32, scalar fp32 out.
#define B_DIM 8
#define N_DIM 8192
#define D_DIM 512
#define CHUNKS 128                   // K1 grid = B*CHUNKS = 1024 blocks
#define NBLOCKS (B_DIM * CHUNKS)
#define ACC_N (B_DIM * D_DIM)        // 4096 fixed-point accumulators
#define FIX_SCALE 68719476736.0      // 2^36

typedef float fx4 __attribute__((ext_vector_type(4)));

// K0: zero the fixed-point accumulators + ticket (stream-ordered before K1).
__global__ __launch_bounds__(512) void k0_zero(unsigned long long* __restrict__ acc) {
    const int i = blockIdx.x * 512 + threadIdx.x;
    if (i <= ACC_N) acc[i] = 0ULL;   // [ACC_N] is the ticket slot
}

// K1: 256 threads (4 waves). Each wave processes 16 consecutive rows,
// 4 rows per iteration; lane l owns d-slice [8l, 8l+8).
// Epilogue: LDS-combine the 4 waves, fixed-point atomicAdd per (b,d);
// last-ticket block computes the final scalar.
__global__ __launch_bounds__(256) void k1_fused(const float* __restrict__ x,
                                                unsigned long long* __restrict__ acc,
                                                float* __restrict__ out) {
    const int blk   = blockIdx.x;
    const int b     = blk >> 7;            // / CHUNKS
    const int chunk = blk & (CHUNKS - 1);
    const int wave  = threadIdx.x >> 6;    // 0..3
    const int lane  = threadIdx.x & 63;
    const int rowsPerChunk = N_DIM / CHUNKS;      // 64
    const int rowsPerWave  = rowsPerChunk >> 2;   // 16

    const long long rowStart = (long long)b * N_DIM
                             + (long long)chunk * rowsPerChunk
                             + (long long)wave * rowsPerWave;

    float accv[8];
    #pragma unroll
    for (int k = 0; k < 8; ++k) accv[k] = 0.0f;

    const float* base = x + rowStart * D_DIM + lane * 8;

    for (int r = 0; r < rowsPerWave; r += 4) {
        fx4 v[4][2];
        #pragma unroll
        for (int i = 0; i < 4; ++i) {
            v[i][0] = *(const fx4*)(base + i * D_DIM);
            v[i][1] = *(const fx4*)(base + i * D_DIM + 4);
        }
        base += 4 * D_DIM;

        float ss[4];
        #pragma unroll
        for (int i = 0; i < 4; ++i) {
            ss[i] = v[i][0].x*v[i][0].x + v[i][0].y*v[i][0].y
                  + v[i][0].z*v[i][0].z + v[i][0].w*v[i][0].w
                  + v[i][1].x*v[i][1].x + v[i][1].y*v[i][1].y
                  + v[i][1].z*v[i][1].z + v[i][1].w*v[i][1].w;
        }

        // four interleaved 64-lane butterflies (independent chains)
        #pragma unroll
        for (int off = 1; off < 64; off <<= 1) {
            #pragma unroll
            for (int i = 0; i < 4; ++i) ss[i] += __shfl_xor(ss[i], off);
        }

        #pragma unroll
        for (int i = 0; i < 4; ++i) {
            const float inv = 1.0f / fmaxf(sqrtf(ss[i]), EPS);
            accv[0] += v[i][0].x * inv;
            accv[1] += v[i][0].y * inv;
            accv[2] += v[i][0].z * inv;
            accv[3] += v[i][0].w * inv;
            accv[4] += v[i][1].x * inv;
            accv[5] += v[i][1].y * inv;
            accv[6] += v[i][1].z * inv;
            accv[7] += v[i][1].w * inv;
        }
    }

    // combine the 4 waves' partials deterministically via LDS
    __shared__ float lds[4][D_DIM];
    float* dst = &lds[wave][lane * 8];
    #pragma unroll
    for (int k = 0; k < 8; ++k) dst[k] = accv[k];
    __syncthreads();

    // fixed-point atomic accumulation per (b,d): order-independent => deterministic
    for (int d = threadIdx.x; d < D_DIM; d += 256) {
        const float s = lds[0][d] + lds[1][d] + lds[2][d] + lds[3][d];
        const long long q = (long long)((double)s * FIX_SCALE);
        atomicAdd(&acc[b * D_DIM + d], (unsigned long long)q);
    }
    __threadfence();
    __syncthreads();

    __shared__ unsigned int lastFlag;
    if (threadIdx.x == 0) {
        const unsigned int t = atomicAdd((unsigned int*)&acc[ACC_N], 1U);
        lastFlag = (t == NBLOCKS - 1) ? 1U : 0U;
    }
    __syncthreads();

    if (lastFlag) {
        // final: sum of squares over all 4096 (b,d) accumulators
        double v = 0.0;
        for (int i = threadIdx.x; i < ACC_N; i += 256) {
            const unsigned long long u =
                __hip_atomic_load(&acc[i], __ATOMIC_RELAXED, __HIP_MEMORY_SCOPE_AGENT);
            const double s = (double)(long long)u / FIX_SCALE;
            v += s * s;
        }
        #pragma unroll
        for (int off = 1; off < 64; off <<= 1)
            v += __shfl_xor(v, off);

        __shared__ double wsum[4];
        if (lane == 0) wsum[wave] = v;
        __syncthreads();
        if (threadIdx.x == 0) {
            const double tot = wsum[0] + wsum[1] + wsum[2] + wsum[3];
            out[0] = (float)(tot / ((double)N_DIM * (double)N_DIM * (double)B_DIM));
        }
    }
}

extern "C" void kernel_launch(void* const* d_in, const int* in_sizes, int n_in,
                              void* d_out, int out_size, void* d_ws, size_t ws_size,
                              hipStream_t stream) {
    const float* x = (const float*)d_in[0];
    float* out = (float*)d_out;

    unsigned long long* acc = (unsigned long long*)d_ws;   // ACC_N + 1 ticket

    k0_zero<<<dim3((ACC_N + 1 + 511) / 512), dim3(512), 0, stream>>>(acc);
    k1_fused<<<dim3(NBLOCKS), dim3(256), 0, stream>>>(x, acc, out);
}

// Round 9
// 37.253 us; speedup vs baseline: 3.9487x; 3.9487x over previous
//
#include <hip/hip_runtime.h>

#define EPS 1e-8f

// Shapes fixed per reference: x [B=8, N=8192, D=512] fp32, scalar fp32 out.
#define B_DIM 8
#define N_DIM 8192
#define D_DIM 512
#define CHUNKS 128   // K1 grid = B*CHUNKS = 1024 blocks (4/CU, 16 waves/CU)
#define FIX_SCALE 1099511627776.0   // 2^40 fixed-point scale for deterministic sum

typedef float fx4 __attribute__((ext_vector_type(4)));

// K1: 256 threads (4 waves). Each wave: 16 rows, 4 rows/iteration, register
// double-buffer so the next 8 loads are in flight during current compute
// (counted vmcnt instead of drain-to-0). Lane l owns d-slice [8l, 8l+8).
// Block 0 zeroes the K2 accumulator/ticket (stream order guarantees K1 < K2).
__global__ __launch_bounds__(256) void k1_partial(const float* __restrict__ x,
                                                  float* __restrict__ partial,
                                                  unsigned long long* __restrict__ acc,
                                                  unsigned int* __restrict__ ticket) {
    if (blockIdx.x == 0 && threadIdx.x == 0) { *acc = 0ULL; *ticket = 0U; }

    const int blk   = blockIdx.x;
    const int b     = blk >> 7;            // / CHUNKS
    const int chunk = blk & (CHUNKS - 1);
    const int wave  = threadIdx.x >> 6;    // 0..3
    const int lane  = threadIdx.x & 63;
    const int rowsPerChunk = N_DIM / CHUNKS;      // 64
    const int rowsPerWave  = rowsPerChunk >> 2;   // 16 -> 4 iterations of 4 rows

    const long long rowStart = (long long)b * N_DIM
                             + (long long)chunk * rowsPerChunk
                             + (long long)wave * rowsPerWave;

    float accv[8];
    #pragma unroll
    for (int k = 0; k < 8; ++k) accv[k] = 0.0f;

    const float* base = x + rowStart * D_DIM + lane * 8;

    fx4 v[2][4][2];

    // prologue: buffer 0 <- rows 0..3
    #pragma unroll
    for (int i = 0; i < 4; ++i) {
        v[0][i][0] = *(const fx4*)(base + i * D_DIM);
        v[0][i][1] = *(const fx4*)(base + i * D_DIM + 4);
    }
    base += 4 * D_DIM;

    #pragma unroll
    for (int it = 0; it < 4; ++it) {
        const int cur = it & 1;
        const int nxt = cur ^ 1;

        if (it < 3) {   // compile-time branch after full unroll
            #pragma unroll
            for (int i = 0; i < 4; ++i) {
                v[nxt][i][0] = *(const fx4*)(base + i * D_DIM);
                v[nxt][i][1] = *(const fx4*)(base + i * D_DIM + 4);
            }
            base += 4 * D_DIM;
        }

        float ss[4];
        #pragma unroll
        for (int i = 0; i < 4; ++i) {
            ss[i] = v[cur][i][0].x*v[cur][i][0].x + v[cur][i][0].y*v[cur][i][0].y
                  + v[cur][i][0].z*v[cur][i][0].z + v[cur][i][0].w*v[cur][i][0].w
                  + v[cur][i][1].x*v[cur][i][1].x + v[cur][i][1].y*v[cur][i][1].y
                  + v[cur][i][1].z*v[cur][i][1].z + v[cur][i][1].w*v[cur][i][1].w;
        }

        // four interleaved 64-lane butterflies (independent chains)
        #pragma unroll
        for (int off = 1; off < 64; off <<= 1) {
            #pragma unroll
            for (int i = 0; i < 4; ++i) ss[i] += __shfl_xor(ss[i], off);
        }

        #pragma unroll
        for (int i = 0; i < 4; ++i) {
            const float inv = 1.0f / fmaxf(sqrtf(ss[i]), EPS);
            accv[0] += v[cur][i][0].x * inv;
            accv[1] += v[cur][i][0].y * inv;
            accv[2] += v[cur][i][0].z * inv;
            accv[3] += v[cur][i][0].w * inv;
            accv[4] += v[cur][i][1].x * inv;
            accv[5] += v[cur][i][1].y * inv;
            accv[6] += v[cur][i][1].z * inv;
            accv[7] += v[cur][i][1].w * inv;
        }
    }

    // combine the 4 waves' partials deterministically via LDS
    __shared__ float lds[4][D_DIM];
    float* dst = &lds[wave][lane * 8];
    #pragma unroll
    for (int k = 0; k < 8; ++k) dst[k] = accv[k];
    __syncthreads();

    for (int d = threadIdx.x; d < D_DIM; d += 256) {
        float s = lds[0][d] + lds[1][d] + lds[2][d] + lds[3][d];
        partial[(long long)blk * D_DIM + d] = s;
    }
}

// K2: 64 blocks = 8 batches x 8 d-groups (64 d's each), 256 threads.
// Wave q sums chunks c === q (mod 4); LDS-combine, square, 64-lane reduce ->
// block ssq. Fixed-point u64 atomic add (order-independent = deterministic);
// ticket-63 block writes the final scalar.
__global__ __launch_bounds__(256) void k2_batch(const float* __restrict__ partial,
                                                unsigned long long* __restrict__ acc,
                                                unsigned int* __restrict__ ticket,
                                                float* __restrict__ out) {
    const int b  = blockIdx.x >> 3;
    const int g  = blockIdx.x & 7;
    const int dl = threadIdx.x & 63;
    const int q  = threadIdx.x >> 6;
    const int d  = g * 64 + dl;

    float s = 0.0f;
    const float* p = partial + (long long)b * CHUNKS * D_DIM + d;
    for (int c = q; c < CHUNKS; c += 4) s += p[(long long)c * D_DIM];

    __shared__ float lds[4][64];
    lds[q][dl] = s;
    __syncthreads();

    if (q == 0) {
        const float tot = lds[0][dl] + lds[1][dl] + lds[2][dl] + lds[3][dl];
        float v = tot * tot;
        #pragma unroll
        for (int off = 1; off < 64; off <<= 1) v += __shfl_xor(v, off);

        if (dl == 0) {
            const long long q64 = (long long)((double)v * FIX_SCALE);
            atomicAdd(acc, (unsigned long long)q64);
            __threadfence();
            const unsigned int t = atomicAdd(ticket, 1U);
            if (t == (B_DIM * 8 - 1)) {
                const unsigned long long totu = atomicAdd(acc, 0ULL);
                const double tot_d = (double)(long long)totu / FIX_SCALE;
                out[0] = (float)(tot_d / ((double)N_DIM * (double)N_DIM * (double)B_DIM));
            }
        }
    }
}

extern "C" void kernel_launch(void* const* d_in, const int* in_sizes, int n_in,
                              void* d_out, int out_size, void* d_ws, size_t ws_size,
                              hipStream_t stream) {
    const float* x = (const float*)d_in[0];
    float* out = (float*)d_out;

    float* partial = (float*)d_ws;                                  // B*CHUNKS*512 floats = 2 MB
    unsigned long long* acc = (unsigned long long*)((char*)d_ws +
                              (size_t)B_DIM * CHUNKS * D_DIM * sizeof(float));
    unsigned int* ticket = (unsigned int*)(acc + 1);

    k1_partial<<<dim3(B_DIM * CHUNKS), dim3(256), 0, stream>>>(x, partial, acc, ticket);
    k2_batch<<<dim3(B_DIM * 8), dim3(256), 0, stream>>>(partial, acc, ticket, out);
}